// Round 9
// baseline (323.332 us; speedup 1.0000x reference)
//
#include <hip/hip_runtime.h>
#include <hip/hip_bf16.h>

// GAT 2-layer, N=50000, E=800000, D=128, H=2, F=128, C=H*F=256.
// Round 9: aggregate VALU diet. xprep precomputes per-edge alpha = x/den
// (CSR order); aggregate hot loop = pure alpha-weighted gather-sum:
// 2 edges/iter (half-wave each), dwordx4 16B/lane, shfl_xor(32) merge,
// persistent 2048-block grid. GEMM (LDS-staged bf16x3 MFMA) and CSR build
// unchanged from round 8.

#define NEG_SLOPE 0.2f

typedef __attribute__((ext_vector_type(8))) short bf16x8_t;
typedef __attribute__((ext_vector_type(4))) float f32x4_t;

__device__ __forceinline__ unsigned short f2bf(float f) {
  union { float f; unsigned int u; } v; v.f = f;
  unsigned int r = v.u + 0x7FFFu + ((v.u >> 16) & 1u);
  return (unsigned short)(r >> 16);
}
__device__ __forceinline__ float bfbits(unsigned int hi16) {
  union { unsigned int u; float f; } v; v.u = hi16;
  return v.f;
}

// ---------------- CSR build ----------------

__global__ void hist_kernel(const int* __restrict__ dst, int* __restrict__ counts, int n_edges) {
  int e = blockIdx.x * blockDim.x + threadIdx.x;
  if (e < n_edges) atomicAdd(&counts[dst[e]], 1);
}

__global__ __launch_bounds__(256) void scan1_kernel(const int* __restrict__ counts,
                                                    int* __restrict__ blocksum, int n) {
  __shared__ int wsum[4];
  int t = threadIdx.x;
  int i0 = blockIdx.x * 1024 + t * 4;
  int s = 0;
  if (i0 + 3 < n) {
    int4 c = *(const int4*)&counts[i0];
    s = c.x + c.y + c.z + c.w;
  } else {
    #pragma unroll
    for (int i = 0; i < 4; ++i) if (i0 + i < n) s += counts[i0 + i];
  }
  int v = s;
  #pragma unroll
  for (int off = 1; off < 64; off <<= 1) v += __shfl_xor(v, off);
  if ((t & 63) == 0) wsum[t >> 6] = v;
  __syncthreads();
  if (t == 0) blocksum[blockIdx.x] = wsum[0] + wsum[1] + wsum[2] + wsum[3];
}

__global__ __launch_bounds__(256) void scan2_kernel(const int* __restrict__ blocksum,
                                                    int* __restrict__ blockoff, int nb,
                                                    int* __restrict__ offsets, int n) {
  __shared__ int wsum[4];
  int t = threadIdx.x;
  int v = (t < nb) ? blocksum[t] : 0;
  int lane = t & 63, wid = t >> 6;
  int inc = v;
  #pragma unroll
  for (int off = 1; off < 64; off <<= 1) {
    int u = __shfl_up(inc, off);
    if (lane >= off) inc += u;
  }
  if (lane == 63) wsum[wid] = inc;
  __syncthreads();
  int wbase = 0;
  for (int w = 0; w < wid; ++w) wbase += wsum[w];
  if (t < nb) blockoff[t] = wbase + inc - v;   // exclusive
  if (t == 255) offsets[n] = wbase + inc;      // grand total
}

__global__ __launch_bounds__(256) void scan3_kernel(const int* __restrict__ counts,
                                                    const int* __restrict__ blockoff,
                                                    int* __restrict__ offsets,
                                                    int* __restrict__ cursor, int n) {
  __shared__ int wsum[4];
  int t = threadIdx.x;
  int i0 = blockIdx.x * 1024 + t * 4;
  int c0 = 0, c1 = 0, c2 = 0, c3 = 0;
  if (i0 + 3 < n) {
    int4 c = *(const int4*)&counts[i0];
    c0 = c.x; c1 = c.y; c2 = c.z; c3 = c.w;
  } else {
    if (i0 + 0 < n) c0 = counts[i0 + 0];
    if (i0 + 1 < n) c1 = counts[i0 + 1];
    if (i0 + 2 < n) c2 = counts[i0 + 2];
    if (i0 + 3 < n) c3 = counts[i0 + 3];
  }
  int s = c0 + c1 + c2 + c3;
  int lane = t & 63, wid = t >> 6;
  int inc = s;
  #pragma unroll
  for (int off = 1; off < 64; off <<= 1) {
    int u = __shfl_up(inc, off);
    if (lane >= off) inc += u;
  }
  if (lane == 63) wsum[wid] = inc;
  __syncthreads();
  int wbase = 0;
  for (int w = 0; w < wid; ++w) wbase += wsum[w];
  int o0 = blockoff[blockIdx.x] + wbase + (inc - s);
  int o1 = o0 + c0, o2 = o1 + c1, o3 = o2 + c2;
  if (i0 + 3 < n) {
    *(int4*)&offsets[i0] = make_int4(o0, o1, o2, o3);
    *(int4*)&cursor[i0]  = make_int4(o0, o1, o2, o3);
  } else {
    if (i0 + 0 < n) { offsets[i0 + 0] = o0; cursor[i0 + 0] = o0; }
    if (i0 + 1 < n) { offsets[i0 + 1] = o1; cursor[i0 + 1] = o1; }
    if (i0 + 2 < n) { offsets[i0 + 2] = o2; cursor[i0 + 2] = o2; }
    if (i0 + 3 < n) { offsets[i0 + 3] = o3; cursor[i0 + 3] = o3; }
  }
}

// scatter: writes src id directly into CSR slot
__global__ void scatter_kernel(const int* __restrict__ src, const int* __restrict__ dst,
                               int* __restrict__ cursor, int* __restrict__ srcp, int n_edges) {
  int e = blockIdx.x * blockDim.x + threadIdx.x;
  if (e < n_edges) {
    int p = atomicAdd(&cursor[dst[e]], 1);
    srcp[p] = src[e];
  }
}

// ---------------- W pack: fp32 -> bf16 hi/lo in B-fragment order ----------------

__global__ __launch_bounds__(256) void wpack_kernel(const float* __restrict__ Ws,
                                                    unsigned short* __restrict__ Whi,
                                                    unsigned short* __restrict__ Wlo) {
  int t = blockIdx.x * 256 + threadIdx.x;   // 8192 threads: 2 lay x 4 s x 16 ct x 64 lane
  int lane = t & 63;
  int ct = (t >> 6) & 15;
  int s = (t >> 10) & 3;
  int lay = t >> 12;
  int col = ct * 16 + (lane & 15);
  int kbase = s * 32 + (lane >> 4) * 8;
  size_t obase = (size_t)t * 8;
  #pragma unroll
  for (int j = 0; j < 8; ++j) {
    float w = Ws[(size_t)lay * 32768 + (size_t)(kbase + j) * 256 + col];
    unsigned short hb = f2bf(w);
    float rem = w - bfbits((unsigned int)hb << 16);
    Whi[obase + j] = hb;
    Wlo[obase + j] = f2bf(rem);
  }
}

// ---------------- MFMA GEMM: feat = h @ W (bf16x3), fused el/er ----------------

__global__ __launch_bounds__(256) void gemm_feat_kernel(
    const float* __restrict__ hin,
    const unsigned short* __restrict__ Whi, const unsigned short* __restrict__ Wlo,
    const float* __restrict__ al, const float* __restrict__ ar,
    unsigned short* __restrict__ featb, float* __restrict__ el, float* __restrict__ er,
    int n_nodes)
{
  __shared__ unsigned short lds_bh[8192];   // 16 ct x 64 lane x 8
  __shared__ unsigned short lds_bl[8192];
  const int tid = threadIdx.x;
  const int w = tid >> 6;
  const int lane = tid & 63;
  const int lrow = lane & 15;
  const int g = lane >> 4;
  const int node0 = blockIdx.x * 64 + w * 16;

  f32x4_t acc[16];
  #pragma unroll
  for (int i = 0; i < 16; ++i) acc[i] = (f32x4_t){0.f, 0.f, 0.f, 0.f};

  int arow = node0 + lrow;
  int arow_c = (arow < n_nodes) ? arow : (n_nodes - 1);
  const float* aptr = hin + (size_t)arow_c * 128 + g * 8;

  for (int s = 0; s < 4; ++s) {
    float4 f0 = *(const float4*)(aptr + s * 32);
    float4 f1 = *(const float4*)(aptr + s * 32 + 4);
    float fv[8] = {f0.x, f0.y, f0.z, f0.w, f1.x, f1.y, f1.z, f1.w};
    bf16x8_t ahi, alo;
    #pragma unroll
    for (int j = 0; j < 8; ++j) {
      unsigned short hb = f2bf(fv[j]);
      float rem = fv[j] - bfbits((unsigned int)hb << 16);
      ahi[j] = (short)hb;
      alo[j] = (short)f2bf(rem);
    }
    __syncthreads();   // previous chunk fully consumed
    const uint4* gh = (const uint4*)(Whi + (size_t)s * 8192);
    const uint4* gl = (const uint4*)(Wlo + (size_t)s * 8192);
    uint4* lh = (uint4*)lds_bh;
    uint4* ll = (uint4*)lds_bl;
    #pragma unroll
    for (int r = 0; r < 4; ++r) {
      lh[tid + 256 * r] = gh[tid + 256 * r];
      ll[tid + 256 * r] = gl[tid + 256 * r];
    }
    __syncthreads();
    #pragma unroll
    for (int ct = 0; ct < 16; ++ct) {
      bf16x8_t bh = *(const bf16x8_t*)&lds_bh[(ct * 64 + lane) * 8];
      bf16x8_t bl = *(const bf16x8_t*)&lds_bl[(ct * 64 + lane) * 8];
      acc[ct] = __builtin_amdgcn_mfma_f32_16x16x32_bf16(ahi, bh, acc[ct], 0, 0, 0);
      acc[ct] = __builtin_amdgcn_mfma_f32_16x16x32_bf16(alo, bh, acc[ct], 0, 0, 0);
      acc[ct] = __builtin_amdgcn_mfma_f32_16x16x32_bf16(ahi, bl, acc[ct], 0, 0, 0);
    }
  }

  float alc[16], arc[16];
  #pragma unroll
  for (int ct = 0; ct < 16; ++ct) {
    alc[ct] = al[ct * 16 + lrow];
    arc[ct] = ar[ct * 16 + lrow];
  }
  #pragma unroll
  for (int r = 0; r < 4; ++r) {
    int orow = node0 + g * 4 + r;
    bool ok = orow < n_nodes;
    float pl0 = 0.f, pl1 = 0.f, pr0 = 0.f, pr1 = 0.f;
    #pragma unroll
    for (int ct = 0; ct < 16; ++ct) {
      float v = acc[ct][r];
      if (ct < 8) { pl0 += v * alc[ct]; pr0 += v * arc[ct]; }
      else        { pl1 += v * alc[ct]; pr1 += v * arc[ct]; }
      if (ok) featb[(size_t)orow * 256 + ct * 16 + lrow] = f2bf(v);
    }
    #pragma unroll
    for (int off = 1; off < 16; off <<= 1) {
      pl0 += __shfl_xor(pl0, off);
      pl1 += __shfl_xor(pl1, off);
      pr0 += __shfl_xor(pr0, off);
      pr1 += __shfl_xor(pr1, off);
    }
    if (lrow == 0 && ok) {
      *(float2*)&el[(size_t)orow * 2] = make_float2(pl0, pl1);
      *(float2*)&er[(size_t)orow * 2] = make_float2(pr0, pr1);
    }
  }
}

// ---------------- xprep: per-edge alpha = exp(leaky(el+er))/den, CSR order ----
// Wave per node. Pass 1: x values + den wave-reduce; pass 2: rescale in place.

__global__ __launch_bounds__(256) void xprep_kernel(
    const float* __restrict__ el, const float* __restrict__ er,
    const int* __restrict__ srcp, const int* __restrict__ offsets,
    float2* __restrict__ alpha, int n_nodes)
{
  int node = blockIdx.x * 4 + (threadIdx.x >> 6);
  int lane = threadIdx.x & 63;
  if (node >= n_nodes) return;
  int beg = offsets[node];
  int end = offsets[node + 1];
  if (beg >= end) return;
  float2 ern = *(const float2*)&er[(size_t)node * 2];
  float den0 = 0.f, den1 = 0.f;
  for (int j = beg + lane; j < end; j += 64) {
    int s = srcp[j];
    float2 l = *(const float2*)&el[(size_t)s * 2];
    float e0 = l.x + ern.x;
    float e1 = l.y + ern.y;
    e0 = fminf((e0 >= 0.f) ? e0 : NEG_SLOPE * e0, 60.f);
    e1 = fminf((e1 >= 0.f) ? e1 : NEG_SLOPE * e1, 60.f);
    float x0 = __expf(e0), x1 = __expf(e1);
    alpha[j] = make_float2(x0, x1);
    den0 += x0; den1 += x1;
  }
  #pragma unroll
  for (int off = 32; off > 0; off >>= 1) {
    den0 += __shfl_xor(den0, off);
    den1 += __shfl_xor(den1, off);
  }
  float inv0 = 1.0f / den0, inv1 = 1.0f / den1;
  for (int j = beg + lane; j < end; j += 64) {
    float2 v = alpha[j];
    alpha[j] = make_float2(v.x * inv0, v.y * inv1);
  }
}

// ---------------- aggregation: pure alpha-weighted gather-sum ----------------
// Persistent grid-stride. Wave = node. 2 edges/iter: half=lane>>5 picks edge,
// c=lane&31 picks 8 cols (c<16 head0, else head1), dwordx4 16B/lane.
// shfl_xor(32) merges half-wave accs; shfl_xor(16) = head partner for hnext.

__global__ __launch_bounds__(256) void aggregate_kernel(
    const unsigned short* __restrict__ featb,
    const float2* __restrict__ alpha,
    const int* __restrict__ srcp, const int* __restrict__ offsets,
    const float* __restrict__ b,
    float* __restrict__ out, float* __restrict__ hnext, int n_nodes)
{
  const int lane = threadIdx.x & 63;
  const int wv = threadIdx.x >> 6;
  const int half = lane >> 5;
  const int c = lane & 31;
  const int ngrp = (n_nodes + 3) >> 2;

  float4 b0 = *(const float4*)&b[c * 8];
  float4 b1 = *(const float4*)&b[c * 8 + 4];

  for (int grp = blockIdx.x; grp < ngrp; grp += gridDim.x) {
    int node = grp * 4 + wv;
    if (node >= n_nodes) continue;
    int beg = offsets[node];
    int end = offsets[node + 1];

    float a0 = 0.f, a1 = 0.f, a2 = 0.f, a3 = 0.f, a4 = 0.f, a5 = 0.f, a6 = 0.f, a7 = 0.f;
    for (int j = beg; j < end; j += 2) {
      int je = j + half;
      bool v = je < end;
      int jc = v ? je : (end - 1);
      int s = srcp[jc];
      float2 al2 = alpha[jc];
      float xs = v ? ((c < 16) ? al2.x : al2.y) : 0.f;
      uint4 q = *(const uint4*)&featb[(size_t)s * 256 + c * 8];
      a0 = fmaf(xs, bfbits(q.x << 16), a0);
      a1 = fmaf(xs, bfbits(q.x & 0xFFFF0000u), a1);
      a2 = fmaf(xs, bfbits(q.y << 16), a2);
      a3 = fmaf(xs, bfbits(q.y & 0xFFFF0000u), a3);
      a4 = fmaf(xs, bfbits(q.z << 16), a4);
      a5 = fmaf(xs, bfbits(q.z & 0xFFFF0000u), a5);
      a6 = fmaf(xs, bfbits(q.w << 16), a6);
      a7 = fmaf(xs, bfbits(q.w & 0xFFFF0000u), a7);
    }
    // merge the two half-wave partials (col index c preserved)
    a0 += __shfl_xor(a0, 32); a1 += __shfl_xor(a1, 32);
    a2 += __shfl_xor(a2, 32); a3 += __shfl_xor(a3, 32);
    a4 += __shfl_xor(a4, 32); a5 += __shfl_xor(a5, 32);
    a6 += __shfl_xor(a6, 32); a7 += __shfl_xor(a7, 32);

    float o0 = a0 + b0.x, o1 = a1 + b0.y, o2 = a2 + b0.z, o3 = a3 + b0.w;
    float o4 = a4 + b1.x, o5 = a5 + b1.y, o6 = a6 + b1.z, o7 = a7 + b1.w;

    if (out) {
      float4 wv4 = half ? make_float4(o4, o5, o6, o7) : make_float4(o0, o1, o2, o3);
      *(float4*)&out[(size_t)node * 256 + c * 8 + half * 4] = wv4;
    }
    if (hnext) {
      // partner cols (other head) live at lane c^16 within the same half
      float p0 = __shfl_xor(o0, 16), p1 = __shfl_xor(o1, 16);
      float p2 = __shfl_xor(o2, 16), p3 = __shfl_xor(o3, 16);
      float p4 = __shfl_xor(o4, 16), p5 = __shfl_xor(o5, 16);
      float p6 = __shfl_xor(o6, 16), p7 = __shfl_xor(o7, 16);
      if (half == 0 && c < 16) {
        float* hp = hnext + (size_t)node * 128 + c * 8;
        *(float4*)hp       = make_float4((o0 + p0) * 0.5f, (o1 + p1) * 0.5f,
                                         (o2 + p2) * 0.5f, (o3 + p3) * 0.5f);
        *(float4*)(hp + 4) = make_float4((o4 + p4) * 0.5f, (o5 + p5) * 0.5f,
                                         (o6 + p6) * 0.5f, (o7 + p7) * 0.5f);
      }
    }
  }
}

// ---------------- launch ----------------

extern "C" void kernel_launch(void* const* d_in, const int* in_sizes, int n_in,
                              void* d_out, int out_size, void* d_ws, size_t ws_size,
                              hipStream_t stream) {
  const float* x   = (const float*)d_in[0];
  const float* Ws  = (const float*)d_in[1];
  const float* als = (const float*)d_in[2];
  const float* ars = (const float*)d_in[3];
  const float* bs  = (const float*)d_in[4];
  const int*   src = (const int*)d_in[5];
  const int*   dst = (const int*)d_in[6];
  const int N = in_sizes[0] / 128;   // 50000
  const int E = in_sizes[5];         // 800000
  float* out = (float*)d_out;

  char* ws = (char*)d_ws;
  auto alloc = [&](size_t bytes) {
    char* p = ws;
    ws += (bytes + 255) & ~(size_t)255;
    return p;
  };
  unsigned short* featb = (unsigned short*)alloc((size_t)N * 256 * 2);
  float* hbuf    = (float*)alloc((size_t)N * 128 * 4);
  float2* alphab = (float2*)alloc((size_t)E * 8);
  int*   srcp    = (int*)alloc((size_t)E * 4);
  int*   offsets = (int*)alloc((size_t)(N + 1) * 4);
  int*   cursor  = (int*)alloc((size_t)N * 4);
  int*   counts  = (int*)alloc((size_t)N * 4);
  float* el      = (float*)alloc((size_t)N * 2 * 4);
  float* er      = (float*)alloc((size_t)N * 2 * 4);
  int*   blocksum = (int*)alloc((size_t)256 * 4);
  int*   blockoff = (int*)alloc((size_t)256 * 4);
  unsigned short* Whi = (unsigned short*)alloc((size_t)65536 * 2);
  unsigned short* Wlo = (unsigned short*)alloc((size_t)65536 * 2);

  const int nb = (N + 1023) / 1024;  // 49

  // CSR by dst (dst invariant across layers: build once)
  hipMemsetAsync(counts, 0, (size_t)N * 4, stream);
  hist_kernel<<<dim3((E + 255) / 256), dim3(256), 0, stream>>>(dst, counts, E);
  scan1_kernel<<<dim3(nb), dim3(256), 0, stream>>>(counts, blocksum, N);
  scan2_kernel<<<dim3(1), dim3(256), 0, stream>>>(blocksum, blockoff, nb, offsets, N);
  scan3_kernel<<<dim3(nb), dim3(256), 0, stream>>>(counts, blockoff, offsets, cursor, N);
  scatter_kernel<<<dim3((E + 255) / 256), dim3(256), 0, stream>>>(src, dst, cursor, srcp, E);

  // pack W (both layers) into MFMA B-fragment order, bf16 hi/lo
  wpack_kernel<<<dim3(32), dim3(256), 0, stream>>>(Ws, Whi, Wlo);

  const int ngrp = (N + 3) / 4;
  for (int l = 0; l < 2; ++l) {
    const float* hin = (l == 0) ? x : hbuf;
    const float* al  = als + (size_t)l * 256;
    const float* ar  = ars + (size_t)l * 256;
    const float* b   = bs  + (size_t)l * 256;
    gemm_feat_kernel<<<dim3((N + 63) / 64), dim3(256), 0, stream>>>(
        hin, Whi + (size_t)l * 32768, Wlo + (size_t)l * 32768,
        al, ar, featb, el, er, N);
    xprep_kernel<<<dim3(ngrp), dim3(256), 0, stream>>>(el, er, srcp, offsets, alphab, N);
    aggregate_kernel<<<dim3(2048), dim3(256), 0, stream>>>(
        featb, alphab, srcp, offsets, b,
        (l == 1) ? out : nullptr,
        (l == 0) ? hbuf : nullptr, N);
  }
}

// Round 11
// 279.689 us; speedup vs baseline: 1.1560x; 1.1560x over previous
//
#include <hip/hip_runtime.h>
#include <hip/hip_bf16.h>

// GAT 2-layer, N=50000, E=800000, D=128, H=2, F=128, C=H*F=256.
// Round 11: round-10 GEMM with the staging-size bug fixed: the 32KB per-buffer
// W slice needs 8 x 256 x 16B copy iterations (r<8), not 4 (r<4 left k>=64
// uninitialized -> absmax 86). Aggregate = round-8 form. CSR build unchanged.

#define NEG_SLOPE 0.2f

typedef __attribute__((ext_vector_type(8))) short bf16x8_t;
typedef __attribute__((ext_vector_type(4))) float f32x4_t;

__device__ __forceinline__ unsigned short f2bf(float f) {
  union { float f; unsigned int u; } v; v.f = f;
  unsigned int r = v.u + 0x7FFFu + ((v.u >> 16) & 1u);
  return (unsigned short)(r >> 16);
}
__device__ __forceinline__ float bfbits(unsigned int hi16) {
  union { unsigned int u; float f; } v; v.u = hi16;
  return v.f;
}

// ---------------- CSR build ----------------

__global__ void hist_kernel(const int* __restrict__ dst, int* __restrict__ counts, int n_edges) {
  int e = blockIdx.x * blockDim.x + threadIdx.x;
  if (e < n_edges) atomicAdd(&counts[dst[e]], 1);
}

__global__ __launch_bounds__(256) void scan1_kernel(const int* __restrict__ counts,
                                                    int* __restrict__ blocksum, int n) {
  __shared__ int wsum[4];
  int t = threadIdx.x;
  int i0 = blockIdx.x * 1024 + t * 4;
  int s = 0;
  if (i0 + 3 < n) {
    int4 c = *(const int4*)&counts[i0];
    s = c.x + c.y + c.z + c.w;
  } else {
    #pragma unroll
    for (int i = 0; i < 4; ++i) if (i0 + i < n) s += counts[i0 + i];
  }
  int v = s;
  #pragma unroll
  for (int off = 1; off < 64; off <<= 1) v += __shfl_xor(v, off);
  if ((t & 63) == 0) wsum[t >> 6] = v;
  __syncthreads();
  if (t == 0) blocksum[blockIdx.x] = wsum[0] + wsum[1] + wsum[2] + wsum[3];
}

__global__ __launch_bounds__(256) void scan2_kernel(const int* __restrict__ blocksum,
                                                    int* __restrict__ blockoff, int nb,
                                                    int* __restrict__ offsets, int n) {
  __shared__ int wsum[4];
  int t = threadIdx.x;
  int v = (t < nb) ? blocksum[t] : 0;
  int lane = t & 63, wid = t >> 6;
  int inc = v;
  #pragma unroll
  for (int off = 1; off < 64; off <<= 1) {
    int u = __shfl_up(inc, off);
    if (lane >= off) inc += u;
  }
  if (lane == 63) wsum[wid] = inc;
  __syncthreads();
  int wbase = 0;
  for (int w = 0; w < wid; ++w) wbase += wsum[w];
  if (t < nb) blockoff[t] = wbase + inc - v;   // exclusive
  if (t == 255) offsets[n] = wbase + inc;      // grand total
}

__global__ __launch_bounds__(256) void scan3_kernel(const int* __restrict__ counts,
                                                    const int* __restrict__ blockoff,
                                                    int* __restrict__ offsets,
                                                    int* __restrict__ cursor, int n) {
  __shared__ int wsum[4];
  int t = threadIdx.x;
  int i0 = blockIdx.x * 1024 + t * 4;
  int c0 = 0, c1 = 0, c2 = 0, c3 = 0;
  if (i0 + 3 < n) {
    int4 c = *(const int4*)&counts[i0];
    c0 = c.x; c1 = c.y; c2 = c.z; c3 = c.w;
  } else {
    if (i0 + 0 < n) c0 = counts[i0 + 0];
    if (i0 + 1 < n) c1 = counts[i0 + 1];
    if (i0 + 2 < n) c2 = counts[i0 + 2];
    if (i0 + 3 < n) c3 = counts[i0 + 3];
  }
  int s = c0 + c1 + c2 + c3;
  int lane = t & 63, wid = t >> 6;
  int inc = s;
  #pragma unroll
  for (int off = 1; off < 64; off <<= 1) {
    int u = __shfl_up(inc, off);
    if (lane >= off) inc += u;
  }
  if (lane == 63) wsum[wid] = inc;
  __syncthreads();
  int wbase = 0;
  for (int w = 0; w < wid; ++w) wbase += wsum[w];
  int o0 = blockoff[blockIdx.x] + wbase + (inc - s);
  int o1 = o0 + c0, o2 = o1 + c1, o3 = o2 + c2;
  if (i0 + 3 < n) {
    *(int4*)&offsets[i0] = make_int4(o0, o1, o2, o3);
    *(int4*)&cursor[i0]  = make_int4(o0, o1, o2, o3);
  } else {
    if (i0 + 0 < n) { offsets[i0 + 0] = o0; cursor[i0 + 0] = o0; }
    if (i0 + 1 < n) { offsets[i0 + 1] = o1; cursor[i0 + 1] = o1; }
    if (i0 + 2 < n) { offsets[i0 + 2] = o2; cursor[i0 + 2] = o2; }
    if (i0 + 3 < n) { offsets[i0 + 3] = o3; cursor[i0 + 3] = o3; }
  }
}

// scatter: writes src id directly into CSR slot
__global__ void scatter_kernel(const int* __restrict__ src, const int* __restrict__ dst,
                               int* __restrict__ cursor, int* __restrict__ srcp, int n_edges) {
  int e = blockIdx.x * blockDim.x + threadIdx.x;
  if (e < n_edges) {
    int p = atomicAdd(&cursor[dst[e]], 1);
    srcp[p] = src[e];
  }
}

// ---------------- W pack: fp32 -> bf16 hi/lo, fragment order per col-half ----
// Layout: [lay][hb][s][ct8][lane][8]; lane holds B[k=s*32+(lane>>4)*8+j]
// [col = hb*128 + ct8*16 + (lane&15)].

__global__ __launch_bounds__(256) void wpack_kernel(const float* __restrict__ Ws,
                                                    unsigned short* __restrict__ Whi,
                                                    unsigned short* __restrict__ Wlo) {
  int t = blockIdx.x * 256 + threadIdx.x;   // 8192 threads
  int t2 = t & 4095;
  int lane = t2 & 63;
  int ct3 = (t2 >> 6) & 7;
  int s = (t2 >> 9) & 3;
  int hb = (t2 >> 11) & 1;
  int lay = t >> 12;
  int col = hb * 128 + ct3 * 16 + (lane & 15);
  int kbase = s * 32 + (lane >> 4) * 8;
  size_t obase = (size_t)lay * 32768 + (size_t)hb * 16384 + (size_t)(t2 & 2047) * 8;
  #pragma unroll
  for (int j = 0; j < 8; ++j) {
    float w = Ws[(size_t)lay * 32768 + (size_t)(kbase + j) * 256 + col];
    unsigned short hb16 = f2bf(w);
    float rem = w - bfbits((unsigned int)hb16 << 16);
    Whi[obase + j] = hb16;
    Wlo[obase + j] = f2bf(rem);
  }
}

// ---------------- MFMA GEMM: feat = h @ W (bf16x3), fused el/er --------------
// Grid (ntiles, 2): blockIdx.y = col-half (= head). Block 256 thr = 4 waves,
// 64 nodes x 128 cols. Whi/Wlo slice (32KB+32KB) staged in LDS ONCE (8 x 16B
// per thread per buffer), single barrier, then barrier-free MFMAs.

__global__ __launch_bounds__(256) void gemm_feat_kernel(
    const float* __restrict__ hin,
    const unsigned short* __restrict__ Whi, const unsigned short* __restrict__ Wlo,
    const float* __restrict__ al, const float* __restrict__ ar,
    unsigned short* __restrict__ featb, float* __restrict__ el, float* __restrict__ er,
    int n_nodes)
{
  __shared__ unsigned short lds_bh[16384];   // 32KB: [s][ct8][lane][8]
  __shared__ unsigned short lds_bl[16384];   // 32KB
  const int tid = threadIdx.x;
  const int w = tid >> 6;
  const int lane = tid & 63;
  const int lrow = lane & 15;
  const int g = lane >> 4;
  const int hb = blockIdx.y;
  const int node0 = blockIdx.x * 64 + w * 16;

  // stage W slice (full K, one col-half): 2048 uint4 hi + 2048 lo
  {
    const uint4* gh = (const uint4*)(Whi + (size_t)hb * 16384);
    const uint4* gl = (const uint4*)(Wlo + (size_t)hb * 16384);
    uint4* lh = (uint4*)lds_bh;
    uint4* ll = (uint4*)lds_bl;
    #pragma unroll
    for (int r = 0; r < 8; ++r) {
      lh[tid + 256 * r] = gh[tid + 256 * r];
      ll[tid + 256 * r] = gl[tid + 256 * r];
    }
  }

  // A row load (full K=128, 32B x 4 chunks per lane) + bf16 hi/lo split
  int arow = node0 + lrow;
  int arow_c = (arow < n_nodes) ? arow : (n_nodes - 1);
  const float* aptr = hin + (size_t)arow_c * 128 + g * 8;
  bf16x8_t ahi[4], alo[4];
  #pragma unroll
  for (int s = 0; s < 4; ++s) {
    float4 f0 = *(const float4*)(aptr + s * 32);
    float4 f1 = *(const float4*)(aptr + s * 32 + 4);
    float fv[8] = {f0.x, f0.y, f0.z, f0.w, f1.x, f1.y, f1.z, f1.w};
    #pragma unroll
    for (int j = 0; j < 8; ++j) {
      unsigned short hb16 = f2bf(fv[j]);
      float rem = fv[j] - bfbits((unsigned int)hb16 << 16);
      ahi[s][j] = (short)hb16;
      alo[s][j] = (short)f2bf(rem);
    }
  }

  f32x4_t acc[8];
  #pragma unroll
  for (int i = 0; i < 8; ++i) acc[i] = (f32x4_t){0.f, 0.f, 0.f, 0.f};

  __syncthreads();   // W slice ready

  #pragma unroll
  for (int s = 0; s < 4; ++s) {
    #pragma unroll
    for (int ct = 0; ct < 8; ++ct) {
      bf16x8_t bh = *(const bf16x8_t*)&lds_bh[((s * 8 + ct) * 64 + lane) * 8];
      bf16x8_t bl = *(const bf16x8_t*)&lds_bl[((s * 8 + ct) * 64 + lane) * 8];
      acc[ct] = __builtin_amdgcn_mfma_f32_16x16x32_bf16(ahi[s], bh, acc[ct], 0, 0, 0);
      acc[ct] = __builtin_amdgcn_mfma_f32_16x16x32_bf16(alo[s], bh, acc[ct], 0, 0, 0);
      acc[ct] = __builtin_amdgcn_mfma_f32_16x16x32_bf16(ahi[s], bl, acc[ct], 0, 0, 0);
    }
  }

  // epilogue: bf16 feat store (cols hb*128 + ct*16 + lrow), single-head el/er
  float alc[8], arc[8];
  #pragma unroll
  for (int ct = 0; ct < 8; ++ct) {
    alc[ct] = al[hb * 128 + ct * 16 + lrow];
    arc[ct] = ar[hb * 128 + ct * 16 + lrow];
  }
  #pragma unroll
  for (int r = 0; r < 4; ++r) {
    int orow = node0 + g * 4 + r;
    bool ok = orow < n_nodes;
    float pl = 0.f, pr = 0.f;
    #pragma unroll
    for (int ct = 0; ct < 8; ++ct) {
      float v = acc[ct][r];
      pl += v * alc[ct];
      pr += v * arc[ct];
      if (ok) featb[(size_t)orow * 256 + hb * 128 + ct * 16 + lrow] = f2bf(v);
    }
    #pragma unroll
    for (int off = 1; off < 16; off <<= 1) {
      pl += __shfl_xor(pl, off);
      pr += __shfl_xor(pr, off);
    }
    if (lrow == 0 && ok) {
      el[(size_t)orow * 2 + hb] = pl;
      er[(size_t)orow * 2 + hb] = pr;
    }
  }
}

// ---------------- fused score + aggregation (round-8 form) ----------------

__global__ __launch_bounds__(256) void aggregate_kernel(
    const unsigned short* __restrict__ featb,
    const float* __restrict__ el, const float* __restrict__ er,
    const int* __restrict__ srcp, const int* __restrict__ offsets,
    const float* __restrict__ b,
    float* __restrict__ out, float* __restrict__ hnext, int n_nodes)
{
  int node = blockIdx.x * 4 + (threadIdx.x >> 6);
  int lane = threadIdx.x & 63;
  if (node >= n_nodes) return;
  int beg = offsets[node];
  int end = offsets[node + 1];

  float2 ern = *(const float2*)&er[(size_t)node * 2];
  const bool h0 = (lane < 32);
  const float er_m = h0 ? ern.x : ern.y;

  float4 acc = make_float4(0.f, 0.f, 0.f, 0.f);
  float den = 0.f;

  int j = beg;
  for (; j + 4 <= end; j += 4) {
    int s0 = srcp[j], s1 = srcp[j + 1], s2 = srcp[j + 2], s3 = srcp[j + 3];
    float2 l0 = *(const float2*)&el[(size_t)s0 * 2];
    float2 l1 = *(const float2*)&el[(size_t)s1 * 2];
    float2 l2 = *(const float2*)&el[(size_t)s2 * 2];
    float2 l3 = *(const float2*)&el[(size_t)s3 * 2];
    uint2 q0 = *(const uint2*)&featb[(size_t)s0 * 256 + lane * 4];
    uint2 q1 = *(const uint2*)&featb[(size_t)s1 * 256 + lane * 4];
    uint2 q2 = *(const uint2*)&featb[(size_t)s2 * 256 + lane * 4];
    uint2 q3 = *(const uint2*)&featb[(size_t)s3 * 256 + lane * 4];
    float e0 = (h0 ? l0.x : l0.y) + er_m;
    float e1 = (h0 ? l1.x : l1.y) + er_m;
    float e2 = (h0 ? l2.x : l2.y) + er_m;
    float e3 = (h0 ? l3.x : l3.y) + er_m;
    e0 = fminf((e0 >= 0.f) ? e0 : NEG_SLOPE * e0, 60.f);
    e1 = fminf((e1 >= 0.f) ? e1 : NEG_SLOPE * e1, 60.f);
    e2 = fminf((e2 >= 0.f) ? e2 : NEG_SLOPE * e2, 60.f);
    e3 = fminf((e3 >= 0.f) ? e3 : NEG_SLOPE * e3, 60.f);
    float x0 = __expf(e0), x1 = __expf(e1), x2 = __expf(e2), x3 = __expf(e3);
    den += (x0 + x1) + (x2 + x3);
    acc.x = fmaf(x0, bfbits(q0.x << 16), acc.x);
    acc.y = fmaf(x0, bfbits(q0.x & 0xFFFF0000u), acc.y);
    acc.z = fmaf(x0, bfbits(q0.y << 16), acc.z);
    acc.w = fmaf(x0, bfbits(q0.y & 0xFFFF0000u), acc.w);
    acc.x = fmaf(x1, bfbits(q1.x << 16), acc.x);
    acc.y = fmaf(x1, bfbits(q1.x & 0xFFFF0000u), acc.y);
    acc.z = fmaf(x1, bfbits(q1.y << 16), acc.z);
    acc.w = fmaf(x1, bfbits(q1.y & 0xFFFF0000u), acc.w);
    acc.x = fmaf(x2, bfbits(q2.x << 16), acc.x);
    acc.y = fmaf(x2, bfbits(q2.x & 0xFFFF0000u), acc.y);
    acc.z = fmaf(x2, bfbits(q2.y << 16), acc.z);
    acc.w = fmaf(x2, bfbits(q2.y & 0xFFFF0000u), acc.w);
    acc.x = fmaf(x3, bfbits(q3.x << 16), acc.x);
    acc.y = fmaf(x3, bfbits(q3.x & 0xFFFF0000u), acc.y);
    acc.z = fmaf(x3, bfbits(q3.y << 16), acc.z);
    acc.w = fmaf(x3, bfbits(q3.y & 0xFFFF0000u), acc.w);
  }
  for (; j < end; ++j) {
    int s0 = srcp[j];
    float2 l0 = *(const float2*)&el[(size_t)s0 * 2];
    uint2 q0 = *(const uint2*)&featb[(size_t)s0 * 256 + lane * 4];
    float e0 = (h0 ? l0.x : l0.y) + er_m;
    e0 = fminf((e0 >= 0.f) ? e0 : NEG_SLOPE * e0, 60.f);
    float x0 = __expf(e0);
    den += x0;
    acc.x = fmaf(x0, bfbits(q0.x << 16), acc.x);
    acc.y = fmaf(x0, bfbits(q0.x & 0xFFFF0000u), acc.y);
    acc.z = fmaf(x0, bfbits(q0.y << 16), acc.z);
    acc.w = fmaf(x0, bfbits(q0.y & 0xFFFF0000u), acc.w);
  }

  float4 b4 = *(const float4*)&b[lane * 4];
  float4 o;
  if (end > beg) {
    float inv = 1.0f / den;
    o.x = fmaf(acc.x, inv, b4.x);
    o.y = fmaf(acc.y, inv, b4.y);
    o.z = fmaf(acc.z, inv, b4.z);
    o.w = fmaf(acc.w, inv, b4.w);
  } else {
    o = b4;
  }
  if (out) *(float4*)&out[(size_t)node * 256 + lane * 4] = o;
  if (hnext) {
    float px = __shfl_xor(o.x, 32);
    float py = __shfl_xor(o.y, 32);
    float pz = __shfl_xor(o.z, 32);
    float pw = __shfl_xor(o.w, 32);
    if (lane < 32) {
      float4 hn = make_float4((o.x + px) * 0.5f, (o.y + py) * 0.5f,
                              (o.z + pz) * 0.5f, (o.w + pw) * 0.5f);
      *(float4*)&hnext[(size_t)node * 128 + lane * 4] = hn;
    }
  }
}

// ---------------- launch ----------------

extern "C" void kernel_launch(void* const* d_in, const int* in_sizes, int n_in,
                              void* d_out, int out_size, void* d_ws, size_t ws_size,
                              hipStream_t stream) {
  const float* x   = (const float*)d_in[0];
  const float* Ws  = (const float*)d_in[1];
  const float* als = (const float*)d_in[2];
  const float* ars = (const float*)d_in[3];
  const float* bs  = (const float*)d_in[4];
  const int*   src = (const int*)d_in[5];
  const int*   dst = (const int*)d_in[6];
  const int N = in_sizes[0] / 128;   // 50000
  const int E = in_sizes[5];         // 800000
  float* out = (float*)d_out;

  char* ws = (char*)d_ws;
  auto alloc = [&](size_t bytes) {
    char* p = ws;
    ws += (bytes + 255) & ~(size_t)255;
    return p;
  };
  unsigned short* featb = (unsigned short*)alloc((size_t)N * 256 * 2);
  float* hbuf    = (float*)alloc((size_t)N * 128 * 4);
  int*   srcp    = (int*)alloc((size_t)E * 4);
  int*   offsets = (int*)alloc((size_t)(N + 1) * 4);
  int*   cursor  = (int*)alloc((size_t)N * 4);
  int*   counts  = (int*)alloc((size_t)N * 4);
  float* el      = (float*)alloc((size_t)N * 2 * 4);
  float* er      = (float*)alloc((size_t)N * 2 * 4);
  int*   blocksum = (int*)alloc((size_t)256 * 4);
  int*   blockoff = (int*)alloc((size_t)256 * 4);
  unsigned short* Whi = (unsigned short*)alloc((size_t)65536 * 2);
  unsigned short* Wlo = (unsigned short*)alloc((size_t)65536 * 2);

  const int nb = (N + 1023) / 1024;  // 49

  // CSR by dst (dst invariant across layers: build once)
  hipMemsetAsync(counts, 0, (size_t)N * 4, stream);
  hist_kernel<<<dim3((E + 255) / 256), dim3(256), 0, stream>>>(dst, counts, E);
  scan1_kernel<<<dim3(nb), dim3(256), 0, stream>>>(counts, blocksum, N);
  scan2_kernel<<<dim3(1), dim3(256), 0, stream>>>(blocksum, blockoff, nb, offsets, N);
  scan3_kernel<<<dim3(nb), dim3(256), 0, stream>>>(counts, blockoff, offsets, cursor, N);
  scatter_kernel<<<dim3((E + 255) / 256), dim3(256), 0, stream>>>(src, dst, cursor, srcp, E);

  // pack W (both layers) into per-col-half fragment order, bf16 hi/lo
  wpack_kernel<<<dim3(32), dim3(256), 0, stream>>>(Ws, Whi, Wlo);

  const int ntiles = (N + 63) / 64;  // 782
  for (int l = 0; l < 2; ++l) {
    const float* hin = (l == 0) ? x : hbuf;
    const float* al  = als + (size_t)l * 256;
    const float* ar  = ars + (size_t)l * 256;
    const float* b   = bs  + (size_t)l * 256;
    gemm_feat_kernel<<<dim3(ntiles, 2), dim3(256), 0, stream>>>(
        hin, Whi + (size_t)l * 32768, Wlo + (size_t)l * 32768,
        al, ar, featb, el, er, N);
    aggregate_kernel<<<dim3((N + 3) / 4), dim3(256), 0, stream>>>(
        featb, el, er, srcp, offsets, b,
        (l == 1) ? out : nullptr,
        (l == 0) ? hbuf : nullptr, N);
  }
}

// Round 12
// 279.171 us; speedup vs baseline: 1.1582x; 1.0019x over previous
//
#include <hip/hip_runtime.h>
#include <hip/hip_bf16.h>

// GAT 2-layer, N=50000, E=800000, D=128, H=2, F=128, C=H*F=256.
// Round 12: dispatch-count diet (11 -> 8). init_kernel fuses counts/tstate
// zeroing + wpack; single-pass decoupled-lookback scan replaces scan1/2/3.
// hist / scatter / GEMM (round-11) / aggregate (round-8) byte-identical.

#define NEG_SLOPE 0.2f

typedef __attribute__((ext_vector_type(8))) short bf16x8_t;
typedef __attribute__((ext_vector_type(4))) float f32x4_t;

__device__ __forceinline__ unsigned short f2bf(float f) {
  union { float f; unsigned int u; } v; v.f = f;
  unsigned int r = v.u + 0x7FFFu + ((v.u >> 16) & 1u);
  return (unsigned short)(r >> 16);
}
__device__ __forceinline__ float bfbits(unsigned int hi16) {
  union { unsigned int u; float f; } v; v.u = hi16;
  return v.f;
}

// ---------------- init: zero counts + lookback state, pack W ----------------
// Blocks 0-31: wpack (fp32 -> bf16 hi/lo, per-col-half fragment order).
// Blocks 32+: zero counts[n] and tstate[64].

__global__ __launch_bounds__(256) void init_kernel(
    const float* __restrict__ Ws,
    unsigned short* __restrict__ Whi, unsigned short* __restrict__ Wlo,
    int* __restrict__ counts, unsigned int* __restrict__ tstate, int n)
{
  const int b = blockIdx.x;
  const int t = threadIdx.x;
  if (b < 32) {
    int tg = b * 256 + t;            // 8192 threads
    int t2 = tg & 4095;
    int lane = t2 & 63;
    int ct3 = (t2 >> 6) & 7;
    int s = (t2 >> 9) & 3;
    int hb = (t2 >> 11) & 1;
    int lay = tg >> 12;
    int col = hb * 128 + ct3 * 16 + (lane & 15);
    int kbase = s * 32 + (lane >> 4) * 8;
    size_t obase = (size_t)lay * 32768 + (size_t)hb * 16384 + (size_t)(t2 & 2047) * 8;
    #pragma unroll
    for (int j = 0; j < 8; ++j) {
      float w = Ws[(size_t)lay * 32768 + (size_t)(kbase + j) * 256 + col];
      unsigned short hb16 = f2bf(w);
      float rem = w - bfbits((unsigned int)hb16 << 16);
      Whi[obase + j] = hb16;
      Wlo[obase + j] = f2bf(rem);
    }
  } else {
    int idx = (b - 32) * 256 + t;
    if (idx < n) counts[idx] = 0;
    if (idx < 64) tstate[idx] = 0u;
  }
}

// ---------------- hist ----------------

__global__ void hist_kernel(const int* __restrict__ dst, int* __restrict__ counts, int n_edges) {
  int e = blockIdx.x * blockDim.x + threadIdx.x;
  if (e < n_edges) atomicAdd(&counts[dst[e]], 1);
}

// ---------------- single-pass decoupled-lookback scan ----------------
// 49 blocks x 256 thr; tile = 1024 counts. tstate[b] = flag|value:
// bit30 = PARTIAL, bit31 = PREFIX, low 30 bits = sum (E = 8e5 < 2^30).
// Lookback terminates at block 0 even on PARTIALs; all 49 blocks co-resident.

__global__ __launch_bounds__(256) void scan_kernel(
    const int* __restrict__ counts, int* __restrict__ offsets,
    int* __restrict__ cursor, unsigned int* __restrict__ tstate, int n)
{
  __shared__ int wsum[4];
  __shared__ int s_prefix;
  const int b = blockIdx.x, t = threadIdx.x;
  const int nb = gridDim.x;
  int i0 = b * 1024 + t * 4;
  int c0 = 0, c1 = 0, c2 = 0, c3 = 0;
  if (i0 + 3 < n) {
    int4 c = *(const int4*)&counts[i0];
    c0 = c.x; c1 = c.y; c2 = c.z; c3 = c.w;
  } else {
    if (i0 + 0 < n) c0 = counts[i0 + 0];
    if (i0 + 1 < n) c1 = counts[i0 + 1];
    if (i0 + 2 < n) c2 = counts[i0 + 2];
    if (i0 + 3 < n) c3 = counts[i0 + 3];
  }
  int s = c0 + c1 + c2 + c3;
  int lane = t & 63, wid = t >> 6;
  int inc = s;
  #pragma unroll
  for (int off = 1; off < 64; off <<= 1) {
    int u = __shfl_up(inc, off);
    if (lane >= off) inc += u;
  }
  if (lane == 63) wsum[wid] = inc;
  __syncthreads();
  int wbase = 0;
  for (int w2 = 0; w2 < wid; ++w2) wbase += wsum[w2];
  int total = wsum[0] + wsum[1] + wsum[2] + wsum[3];

  if (t == 0) {
    atomicExch(&tstate[b], 0x40000000u | (unsigned)total);   // PARTIAL
    int prefix = 0;
    int i = b - 1;
    while (i >= 0) {
      unsigned st = atomicAdd(&tstate[i], 0u);
      unsigned fl = st >> 30;
      if (fl == 0u) continue;                 // spin: predecessor not posted
      prefix += (int)(st & 0x3FFFFFFFu);
      if (fl == 2u) break;                    // hit a full prefix
      --i;
    }
    atomicExch(&tstate[b], 0x80000000u | (unsigned)(prefix + total));  // PREFIX
    s_prefix = prefix;
    if (b == nb - 1) offsets[n] = prefix + total;
  }
  __syncthreads();
  int base = s_prefix + wbase + (inc - s);
  int o0 = base, o1 = o0 + c0, o2 = o1 + c1, o3 = o2 + c2;
  if (i0 + 3 < n) {
    *(int4*)&offsets[i0] = make_int4(o0, o1, o2, o3);
    *(int4*)&cursor[i0]  = make_int4(o0, o1, o2, o3);
  } else {
    if (i0 + 0 < n) { offsets[i0 + 0] = o0; cursor[i0 + 0] = o0; }
    if (i0 + 1 < n) { offsets[i0 + 1] = o1; cursor[i0 + 1] = o1; }
    if (i0 + 2 < n) { offsets[i0 + 2] = o2; cursor[i0 + 2] = o2; }
    if (i0 + 3 < n) { offsets[i0 + 3] = o3; cursor[i0 + 3] = o3; }
  }
}

// scatter: writes src id directly into CSR slot
__global__ void scatter_kernel(const int* __restrict__ src, const int* __restrict__ dst,
                               int* __restrict__ cursor, int* __restrict__ srcp, int n_edges) {
  int e = blockIdx.x * blockDim.x + threadIdx.x;
  if (e < n_edges) {
    int p = atomicAdd(&cursor[dst[e]], 1);
    srcp[p] = src[e];
  }
}

// ---------------- MFMA GEMM: feat = h @ W (bf16x3), fused el/er --------------
// Grid (ntiles, 2): blockIdx.y = col-half (= head). Block 256 thr = 4 waves,
// 64 nodes x 128 cols. Whi/Wlo slice (32KB+32KB) staged in LDS ONCE (8 x 16B
// per thread per buffer), single barrier, then barrier-free MFMAs.

__global__ __launch_bounds__(256) void gemm_feat_kernel(
    const float* __restrict__ hin,
    const unsigned short* __restrict__ Whi, const unsigned short* __restrict__ Wlo,
    const float* __restrict__ al, const float* __restrict__ ar,
    unsigned short* __restrict__ featb, float* __restrict__ el, float* __restrict__ er,
    int n_nodes)
{
  __shared__ unsigned short lds_bh[16384];   // 32KB: [s][ct8][lane][8]
  __shared__ unsigned short lds_bl[16384];   // 32KB
  const int tid = threadIdx.x;
  const int w = tid >> 6;
  const int lane = tid & 63;
  const int lrow = lane & 15;
  const int g = lane >> 4;
  const int hb = blockIdx.y;
  const int node0 = blockIdx.x * 64 + w * 16;

  {
    const uint4* gh = (const uint4*)(Whi + (size_t)hb * 16384);
    const uint4* gl = (const uint4*)(Wlo + (size_t)hb * 16384);
    uint4* lh = (uint4*)lds_bh;
    uint4* ll = (uint4*)lds_bl;
    #pragma unroll
    for (int r = 0; r < 8; ++r) {
      lh[tid + 256 * r] = gh[tid + 256 * r];
      ll[tid + 256 * r] = gl[tid + 256 * r];
    }
  }

  int arow = node0 + lrow;
  int arow_c = (arow < n_nodes) ? arow : (n_nodes - 1);
  const float* aptr = hin + (size_t)arow_c * 128 + g * 8;
  bf16x8_t ahi[4], alo[4];
  #pragma unroll
  for (int s = 0; s < 4; ++s) {
    float4 f0 = *(const float4*)(aptr + s * 32);
    float4 f1 = *(const float4*)(aptr + s * 32 + 4);
    float fv[8] = {f0.x, f0.y, f0.z, f0.w, f1.x, f1.y, f1.z, f1.w};
    #pragma unroll
    for (int j = 0; j < 8; ++j) {
      unsigned short hb16 = f2bf(fv[j]);
      float rem = fv[j] - bfbits((unsigned int)hb16 << 16);
      ahi[s][j] = (short)hb16;
      alo[s][j] = (short)f2bf(rem);
    }
  }

  f32x4_t acc[8];
  #pragma unroll
  for (int i = 0; i < 8; ++i) acc[i] = (f32x4_t){0.f, 0.f, 0.f, 0.f};

  __syncthreads();   // W slice ready

  #pragma unroll
  for (int s = 0; s < 4; ++s) {
    #pragma unroll
    for (int ct = 0; ct < 8; ++ct) {
      bf16x8_t bh = *(const bf16x8_t*)&lds_bh[((s * 8 + ct) * 64 + lane) * 8];
      bf16x8_t bl = *(const bf16x8_t*)&lds_bl[((s * 8 + ct) * 64 + lane) * 8];
      acc[ct] = __builtin_amdgcn_mfma_f32_16x16x32_bf16(ahi[s], bh, acc[ct], 0, 0, 0);
      acc[ct] = __builtin_amdgcn_mfma_f32_16x16x32_bf16(alo[s], bh, acc[ct], 0, 0, 0);
      acc[ct] = __builtin_amdgcn_mfma_f32_16x16x32_bf16(ahi[s], bl, acc[ct], 0, 0, 0);
    }
  }

  float alc[8], arc[8];
  #pragma unroll
  for (int ct = 0; ct < 8; ++ct) {
    alc[ct] = al[hb * 128 + ct * 16 + lrow];
    arc[ct] = ar[hb * 128 + ct * 16 + lrow];
  }
  #pragma unroll
  for (int r = 0; r < 4; ++r) {
    int orow = node0 + g * 4 + r;
    bool ok = orow < n_nodes;
    float pl = 0.f, pr = 0.f;
    #pragma unroll
    for (int ct = 0; ct < 8; ++ct) {
      float v = acc[ct][r];
      pl += v * alc[ct];
      pr += v * arc[ct];
      if (ok) featb[(size_t)orow * 256 + hb * 128 + ct * 16 + lrow] = f2bf(v);
    }
    #pragma unroll
    for (int off = 1; off < 16; off <<= 1) {
      pl += __shfl_xor(pl, off);
      pr += __shfl_xor(pr, off);
    }
    if (lrow == 0 && ok) {
      el[(size_t)orow * 2 + hb] = pl;
      er[(size_t)orow * 2 + hb] = pr;
    }
  }
}

// ---------------- fused score + aggregation (round-8 form) ----------------

__global__ __launch_bounds__(256) void aggregate_kernel(
    const unsigned short* __restrict__ featb,
    const float* __restrict__ el, const float* __restrict__ er,
    const int* __restrict__ srcp, const int* __restrict__ offsets,
    const float* __restrict__ b,
    float* __restrict__ out, float* __restrict__ hnext, int n_nodes)
{
  int node = blockIdx.x * 4 + (threadIdx.x >> 6);
  int lane = threadIdx.x & 63;
  if (node >= n_nodes) return;
  int beg = offsets[node];
  int end = offsets[node + 1];

  float2 ern = *(const float2*)&er[(size_t)node * 2];
  const bool h0 = (lane < 32);
  const float er_m = h0 ? ern.x : ern.y;

  float4 acc = make_float4(0.f, 0.f, 0.f, 0.f);
  float den = 0.f;

  int j = beg;
  for (; j + 4 <= end; j += 4) {
    int s0 = srcp[j], s1 = srcp[j + 1], s2 = srcp[j + 2], s3 = srcp[j + 3];
    float2 l0 = *(const float2*)&el[(size_t)s0 * 2];
    float2 l1 = *(const float2*)&el[(size_t)s1 * 2];
    float2 l2 = *(const float2*)&el[(size_t)s2 * 2];
    float2 l3 = *(const float2*)&el[(size_t)s3 * 2];
    uint2 q0 = *(const uint2*)&featb[(size_t)s0 * 256 + lane * 4];
    uint2 q1 = *(const uint2*)&featb[(size_t)s1 * 256 + lane * 4];
    uint2 q2 = *(const uint2*)&featb[(size_t)s2 * 256 + lane * 4];
    uint2 q3 = *(const uint2*)&featb[(size_t)s3 * 256 + lane * 4];
    float e0 = (h0 ? l0.x : l0.y) + er_m;
    float e1 = (h0 ? l1.x : l1.y) + er_m;
    float e2 = (h0 ? l2.x : l2.y) + er_m;
    float e3 = (h0 ? l3.x : l3.y) + er_m;
    e0 = fminf((e0 >= 0.f) ? e0 : NEG_SLOPE * e0, 60.f);
    e1 = fminf((e1 >= 0.f) ? e1 : NEG_SLOPE * e1, 60.f);
    e2 = fminf((e2 >= 0.f) ? e2 : NEG_SLOPE * e2, 60.f);
    e3 = fminf((e3 >= 0.f) ? e3 : NEG_SLOPE * e3, 60.f);
    float x0 = __expf(e0), x1 = __expf(e1), x2 = __expf(e2), x3 = __expf(e3);
    den += (x0 + x1) + (x2 + x3);
    acc.x = fmaf(x0, bfbits(q0.x << 16), acc.x);
    acc.y = fmaf(x0, bfbits(q0.x & 0xFFFF0000u), acc.y);
    acc.z = fmaf(x0, bfbits(q0.y << 16), acc.z);
    acc.w = fmaf(x0, bfbits(q0.y & 0xFFFF0000u), acc.w);
    acc.x = fmaf(x1, bfbits(q1.x << 16), acc.x);
    acc.y = fmaf(x1, bfbits(q1.x & 0xFFFF0000u), acc.y);
    acc.z = fmaf(x1, bfbits(q1.y << 16), acc.z);
    acc.w = fmaf(x1, bfbits(q1.y & 0xFFFF0000u), acc.w);
    acc.x = fmaf(x2, bfbits(q2.x << 16), acc.x);
    acc.y = fmaf(x2, bfbits(q2.x & 0xFFFF0000u), acc.y);
    acc.z = fmaf(x2, bfbits(q2.y << 16), acc.z);
    acc.w = fmaf(x2, bfbits(q2.y & 0xFFFF0000u), acc.w);
    acc.x = fmaf(x3, bfbits(q3.x << 16), acc.x);
    acc.y = fmaf(x3, bfbits(q3.x & 0xFFFF0000u), acc.y);
    acc.z = fmaf(x3, bfbits(q3.y << 16), acc.z);
    acc.w = fmaf(x3, bfbits(q3.y & 0xFFFF0000u), acc.w);
  }
  for (; j < end; ++j) {
    int s0 = srcp[j];
    float2 l0 = *(const float2*)&el[(size_t)s0 * 2];
    uint2 q0 = *(const uint2*)&featb[(size_t)s0 * 256 + lane * 4];
    float e0 = (h0 ? l0.x : l0.y) + er_m;
    e0 = fminf((e0 >= 0.f) ? e0 : NEG_SLOPE * e0, 60.f);
    float x0 = __expf(e0);
    den += x0;
    acc.x = fmaf(x0, bfbits(q0.x << 16), acc.x);
    acc.y = fmaf(x0, bfbits(q0.x & 0xFFFF0000u), acc.y);
    acc.z = fmaf(x0, bfbits(q0.y << 16), acc.z);
    acc.w = fmaf(x0, bfbits(q0.y & 0xFFFF0000u), acc.w);
  }

  float4 b4 = *(const float4*)&b[lane * 4];
  float4 o;
  if (end > beg) {
    float inv = 1.0f / den;
    o.x = fmaf(acc.x, inv, b4.x);
    o.y = fmaf(acc.y, inv, b4.y);
    o.z = fmaf(acc.z, inv, b4.z);
    o.w = fmaf(acc.w, inv, b4.w);
  } else {
    o = b4;
  }
  if (out) *(float4*)&out[(size_t)node * 256 + lane * 4] = o;
  if (hnext) {
    float px = __shfl_xor(o.x, 32);
    float py = __shfl_xor(o.y, 32);
    float pz = __shfl_xor(o.z, 32);
    float pw = __shfl_xor(o.w, 32);
    if (lane < 32) {
      float4 hn = make_float4((o.x + px) * 0.5f, (o.y + py) * 0.5f,
                              (o.z + pz) * 0.5f, (o.w + pw) * 0.5f);
      *(float4*)&hnext[(size_t)node * 128 + lane * 4] = hn;
    }
  }
}

// ---------------- launch ----------------

extern "C" void kernel_launch(void* const* d_in, const int* in_sizes, int n_in,
                              void* d_out, int out_size, void* d_ws, size_t ws_size,
                              hipStream_t stream) {
  const float* x   = (const float*)d_in[0];
  const float* Ws  = (const float*)d_in[1];
  const float* als = (const float*)d_in[2];
  const float* ars = (const float*)d_in[3];
  const float* bs  = (const float*)d_in[4];
  const int*   src = (const int*)d_in[5];
  const int*   dst = (const int*)d_in[6];
  const int N = in_sizes[0] / 128;   // 50000
  const int E = in_sizes[5];         // 800000
  float* out = (float*)d_out;

  char* ws = (char*)d_ws;
  auto alloc = [&](size_t bytes) {
    char* p = ws;
    ws += (bytes + 255) & ~(size_t)255;
    return p;
  };
  unsigned short* featb = (unsigned short*)alloc((size_t)N * 256 * 2);
  float* hbuf    = (float*)alloc((size_t)N * 128 * 4);
  int*   srcp    = (int*)alloc((size_t)E * 4);
  int*   offsets = (int*)alloc((size_t)(N + 1) * 4);
  int*   cursor  = (int*)alloc((size_t)N * 4);
  int*   counts  = (int*)alloc((size_t)N * 4);
  float* el      = (float*)alloc((size_t)N * 2 * 4);
  float* er      = (float*)alloc((size_t)N * 2 * 4);
  unsigned int* tstate = (unsigned int*)alloc((size_t)64 * 4);
  unsigned short* Whi = (unsigned short*)alloc((size_t)65536 * 2);
  unsigned short* Wlo = (unsigned short*)alloc((size_t)65536 * 2);

  const int nb = (N + 1023) / 1024;          // 49 scan tiles
  const int zb = 32 + (N + 255) / 256;       // init grid: 32 wpack + zero blocks

  init_kernel<<<dim3(zb), dim3(256), 0, stream>>>(Ws, Whi, Wlo, counts, tstate, N);
  hist_kernel<<<dim3((E + 255) / 256), dim3(256), 0, stream>>>(dst, counts, E);
  scan_kernel<<<dim3(nb), dim3(256), 0, stream>>>(counts, offsets, cursor, tstate, N);
  scatter_kernel<<<dim3((E + 255) / 256), dim3(256), 0, stream>>>(src, dst, cursor, srcp, E);

  const int ntiles = (N + 63) / 64;  // 782
  for (int l = 0; l < 2; ++l) {
    const float* hin = (l == 0) ? x : hbuf;
    const float* al  = als + (size_t)l * 256;
    const float* ar  = ars + (size_t)l * 256;
    const float* b   = bs  + (size_t)l * 256;
    gemm_feat_kernel<<<dim3(ntiles, 2), dim3(256), 0, stream>>>(
        hin, Whi + (size_t)l * 32768, Wlo + (size_t)l * 32768,
        al, ar, featb, el, er, N);
    aggregate_kernel<<<dim3((N + 3) / 4), dim3(256), 0, stream>>>(
        featb, el, er, srcp, offsets, b,
        (l == 1) ? out : nullptr,
        (l == 0) ? hbuf : nullptr, N);
  }
}

// Round 13
// 272.288 us; speedup vs baseline: 1.1875x; 1.0253x over previous
//
#include <hip/hip_runtime.h>
#include <hip/hip_bf16.h>

// GAT 2-layer, N=50000, E=800000, D=128, H=2, F=128, C=H*F=256.
// Round 13: h-space aggregation (linearity: sum_e a*feat[s] = (sum_e a*h[s])@W).
//  - gather payload halves: bf16 h rows are 256B vs featb's 512B.
//  - el/er = h . (W@al) via precomputed wal/war (fp32-exact score path).
//  - gemm AFTER aggregate; layer1 emits only head-mean hbuf (bf16) + el2/er2.
// Pipeline: init -> hist -> scan -> scatter -> elr1 -> agg -> gemm1 -> agg -> gemm2.

#define NEG_SLOPE 0.2f

typedef __attribute__((ext_vector_type(8))) short bf16x8_t;
typedef __attribute__((ext_vector_type(4))) float f32x4_t;

__device__ __forceinline__ unsigned short f2bf(float f) {
  union { float f; unsigned int u; } v; v.f = f;
  unsigned int r = v.u + 0x7FFFu + ((v.u >> 16) & 1u);
  return (unsigned short)(r >> 16);
}
__device__ __forceinline__ float bfbits(unsigned int hi16) {
  union { unsigned int u; float f; } v; v.u = hi16;
  return v.f;
}

// ---------------- init: wpack + wal/war + x->bf16 + zero counts/tstate -------

__global__ __launch_bounds__(256) void init_kernel(
    const float* __restrict__ Ws, const float* __restrict__ als,
    const float* __restrict__ ars, const float* __restrict__ x,
    unsigned short* __restrict__ Whi, unsigned short* __restrict__ Wlo,
    float* __restrict__ wal, float* __restrict__ war,
    unsigned short* __restrict__ xb16,
    int* __restrict__ counts, unsigned int* __restrict__ tstate, int n)
{
  const int b = blockIdx.x;
  const int t = threadIdx.x;
  const int nxb = (n * 128 + 1023) >> 10;
  if (b < 32) {
    // W pack: [lay][hb][s][ct8][lane][8]; lane holds B[k=s*32+(lane>>4)*8+j]
    // [col = hb*128 + ct8*16 + (lane&15)]
    int tg = b * 256 + t;
    int t2 = tg & 4095;
    int lane = t2 & 63;
    int ct3 = (t2 >> 6) & 7;
    int s = (t2 >> 9) & 3;
    int hb = (t2 >> 11) & 1;
    int lay = tg >> 12;
    int col = hb * 128 + ct3 * 16 + (lane & 15);
    int kbase = s * 32 + (lane >> 4) * 8;
    size_t obase = (size_t)lay * 32768 + (size_t)hb * 16384 + (size_t)(t2 & 2047) * 8;
    #pragma unroll
    for (int j = 0; j < 8; ++j) {
      float w = Ws[(size_t)lay * 32768 + (size_t)(kbase + j) * 256 + col];
      unsigned short hb16 = f2bf(w);
      float rem = w - bfbits((unsigned int)hb16 << 16);
      Whi[obase + j] = hb16;
      Wlo[obase + j] = f2bf(rem);
    }
  } else if (b < 36) {
    // wal[lay][h][k] = sum_f W[lay][k][h*128+f] * al[lay][h][f]; war likewise
    int tg = (b - 32) * 256 + t;           // 0..1023
    int lr = tg >> 9;
    int rem = tg & 511;
    int lay = rem >> 8, h = (rem >> 7) & 1, k = rem & 127;
    const float* a = (lr ? ars : als) + (size_t)lay * 256 + h * 128;
    const float* wrow = Ws + (size_t)lay * 32768 + (size_t)k * 256 + h * 128;
    float sum = 0.f;
    for (int f = 0; f < 128; ++f) sum = fmaf(wrow[f], a[f], sum);
    (lr ? war : wal)[(size_t)lay * 256 + h * 128 + k] = sum;
  } else if (b < 36 + nxb) {
    int idx = (b - 36) * 1024 + t * 4;
    int nf = n * 128;
    if (idx + 3 < nf) {
      float4 v = *(const float4*)&x[idx];
      ushort4 p;
      p.x = f2bf(v.x); p.y = f2bf(v.y); p.z = f2bf(v.z); p.w = f2bf(v.w);
      *(ushort4*)&xb16[idx] = p;
    } else {
      for (int i = 0; i < 4 && idx + i < nf; ++i) xb16[idx + i] = f2bf(x[idx + i]);
    }
  } else {
    int idx = (b - 36 - nxb) * 256 + t;
    if (idx < n) counts[idx] = 0;
    if (idx < 64) tstate[idx] = 0u;
  }
}

// ---------------- hist ----------------

__global__ void hist_kernel(const int* __restrict__ dst, int* __restrict__ counts, int n_edges) {
  int e = blockIdx.x * blockDim.x + threadIdx.x;
  if (e < n_edges) atomicAdd(&counts[dst[e]], 1);
}

// ---------------- single-pass decoupled-lookback scan ----------------

__global__ __launch_bounds__(256) void scan_kernel(
    const int* __restrict__ counts, int* __restrict__ offsets,
    int* __restrict__ cursor, unsigned int* __restrict__ tstate, int n)
{
  __shared__ int wsum[4];
  __shared__ int s_prefix;
  const int b = blockIdx.x, t = threadIdx.x;
  const int nb = gridDim.x;
  int i0 = b * 1024 + t * 4;
  int c0 = 0, c1 = 0, c2 = 0, c3 = 0;
  if (i0 + 3 < n) {
    int4 c = *(const int4*)&counts[i0];
    c0 = c.x; c1 = c.y; c2 = c.z; c3 = c.w;
  } else {
    if (i0 + 0 < n) c0 = counts[i0 + 0];
    if (i0 + 1 < n) c1 = counts[i0 + 1];
    if (i0 + 2 < n) c2 = counts[i0 + 2];
    if (i0 + 3 < n) c3 = counts[i0 + 3];
  }
  int s = c0 + c1 + c2 + c3;
  int lane = t & 63, wid = t >> 6;
  int inc = s;
  #pragma unroll
  for (int off = 1; off < 64; off <<= 1) {
    int u = __shfl_up(inc, off);
    if (lane >= off) inc += u;
  }
  if (lane == 63) wsum[wid] = inc;
  __syncthreads();
  int wbase = 0;
  for (int w2 = 0; w2 < wid; ++w2) wbase += wsum[w2];
  int total = wsum[0] + wsum[1] + wsum[2] + wsum[3];

  if (t == 0) {
    atomicExch(&tstate[b], 0x40000000u | (unsigned)total);   // PARTIAL
    int prefix = 0;
    int i = b - 1;
    while (i >= 0) {
      unsigned st = atomicAdd(&tstate[i], 0u);
      unsigned fl = st >> 30;
      if (fl == 0u) continue;
      prefix += (int)(st & 0x3FFFFFFFu);
      if (fl == 2u) break;
      --i;
    }
    atomicExch(&tstate[b], 0x80000000u | (unsigned)(prefix + total));  // PREFIX
    s_prefix = prefix;
    if (b == nb - 1) offsets[n] = prefix + total;
  }
  __syncthreads();
  int base = s_prefix + wbase + (inc - s);
  int o0 = base, o1 = o0 + c0, o2 = o1 + c1, o3 = o2 + c2;
  if (i0 + 3 < n) {
    *(int4*)&offsets[i0] = make_int4(o0, o1, o2, o3);
    *(int4*)&cursor[i0]  = make_int4(o0, o1, o2, o3);
  } else {
    if (i0 + 0 < n) { offsets[i0 + 0] = o0; cursor[i0 + 0] = o0; }
    if (i0 + 1 < n) { offsets[i0 + 1] = o1; cursor[i0 + 1] = o1; }
    if (i0 + 2 < n) { offsets[i0 + 2] = o2; cursor[i0 + 2] = o2; }
    if (i0 + 3 < n) { offsets[i0 + 3] = o3; cursor[i0 + 3] = o3; }
  }
}

__global__ void scatter_kernel(const int* __restrict__ src, const int* __restrict__ dst,
                               int* __restrict__ cursor, int* __restrict__ srcp, int n_edges) {
  int e = blockIdx.x * blockDim.x + threadIdx.x;
  if (e < n_edges) {
    int p = atomicAdd(&cursor[dst[e]], 1);
    srcp[p] = src[e];
  }
}

// ---------------- elr1: el/er for layer 1 from x ----------------
// el[n,h] = x[n] . wal[0][h]; wave per node, lane c owns cols 2c,2c+1.

__global__ __launch_bounds__(256) void elr_kernel(
    const float* __restrict__ x, const float* __restrict__ wal,
    const float* __restrict__ war, float* __restrict__ el, float* __restrict__ er, int n)
{
  int node = blockIdx.x * 4 + (threadIdx.x >> 6);
  int c = threadIdx.x & 63;
  if (node >= n) return;
  float2 v = *(const float2*)&x[(size_t)node * 128 + c * 2];
  float pl0 = v.x * wal[2 * c] + v.y * wal[2 * c + 1];
  float pl1 = v.x * wal[128 + 2 * c] + v.y * wal[128 + 2 * c + 1];
  float pr0 = v.x * war[2 * c] + v.y * war[2 * c + 1];
  float pr1 = v.x * war[128 + 2 * c] + v.y * war[128 + 2 * c + 1];
  #pragma unroll
  for (int off = 1; off < 64; off <<= 1) {
    pl0 += __shfl_xor(pl0, off);
    pl1 += __shfl_xor(pl1, off);
    pr0 += __shfl_xor(pr0, off);
    pr1 += __shfl_xor(pr1, off);
  }
  if (c == 0) {
    *(float2*)&el[(size_t)node * 2] = make_float2(pl0, pl1);
    *(float2*)&er[(size_t)node * 2] = make_float2(pr0, pr1);
  }
}

// ---------------- h-space aggregation ----------------
// agg[n][h][k] = sum_e alpha[e,h] * h_src[k] (bf16 gather, 256B/row).
// Wave per node; lane c owns cols 2c,2c+1 for BOTH heads; 4-edge unroll.

#define AGG_EDGE(sj, lj, qj)                                        \
  {                                                                 \
    float e0 = lj.x + ern.x, e1 = lj.y + ern.y;                     \
    e0 = fminf((e0 >= 0.f) ? e0 : NEG_SLOPE * e0, 60.f);            \
    e1 = fminf((e1 >= 0.f) ? e1 : NEG_SLOPE * e1, 60.f);            \
    float x0 = __expf(e0), x1 = __expf(e1);                         \
    den0 += x0; den1 += x1;                                         \
    float f0 = bfbits(qj << 16), f1 = bfbits(qj & 0xFFFF0000u);     \
    a00 = fmaf(x0, f0, a00); a01 = fmaf(x0, f1, a01);               \
    a10 = fmaf(x1, f0, a10); a11 = fmaf(x1, f1, a11);               \
  }

__global__ __launch_bounds__(256) void aggregate_kernel(
    const unsigned short* __restrict__ hsrc,   // [N][128] bf16
    const float* __restrict__ el, const float* __restrict__ er,
    const int* __restrict__ srcp, const int* __restrict__ offsets,
    float* __restrict__ agg, int n_nodes)
{
  int node = blockIdx.x * 4 + (threadIdx.x >> 6);
  int c = threadIdx.x & 63;
  if (node >= n_nodes) return;
  int beg = offsets[node];
  int end = offsets[node + 1];
  float2 ern = *(const float2*)&er[(size_t)node * 2];

  float a00 = 0.f, a01 = 0.f, a10 = 0.f, a11 = 0.f, den0 = 0.f, den1 = 0.f;
  int j = beg;
  for (; j + 4 <= end; j += 4) {
    int s0 = srcp[j], s1 = srcp[j + 1], s2 = srcp[j + 2], s3 = srcp[j + 3];
    float2 l0 = *(const float2*)&el[(size_t)s0 * 2];
    float2 l1 = *(const float2*)&el[(size_t)s1 * 2];
    float2 l2 = *(const float2*)&el[(size_t)s2 * 2];
    float2 l3 = *(const float2*)&el[(size_t)s3 * 2];
    unsigned int q0 = *(const unsigned int*)&hsrc[(size_t)s0 * 128 + c * 2];
    unsigned int q1 = *(const unsigned int*)&hsrc[(size_t)s1 * 128 + c * 2];
    unsigned int q2 = *(const unsigned int*)&hsrc[(size_t)s2 * 128 + c * 2];
    unsigned int q3 = *(const unsigned int*)&hsrc[(size_t)s3 * 128 + c * 2];
    AGG_EDGE(s0, l0, q0)
    AGG_EDGE(s1, l1, q1)
    AGG_EDGE(s2, l2, q2)
    AGG_EDGE(s3, l3, q3)
  }
  for (; j < end; ++j) {
    int s0 = srcp[j];
    float2 l0 = *(const float2*)&el[(size_t)s0 * 2];
    unsigned int q0 = *(const unsigned int*)&hsrc[(size_t)s0 * 128 + c * 2];
    AGG_EDGE(s0, l0, q0)
  }

  float2 o0 = make_float2(0.f, 0.f), o1 = make_float2(0.f, 0.f);
  if (end > beg) {
    float i0 = 1.0f / den0, i1 = 1.0f / den1;
    o0 = make_float2(a00 * i0, a01 * i0);
    o1 = make_float2(a10 * i1, a11 * i1);
  }
  *(float2*)&agg[(size_t)node * 256 + c * 2]       = o0;
  *(float2*)&agg[(size_t)node * 256 + 128 + c * 2] = o1;
}

// ---------------- gemm1: hbuf = 0.5*(agg0@W0 + agg1@W1) + bmean; el2/er2 ------
// K=256 (two 128-chunks, slice staged per chunk); 128 out cols; bf16x3.

__global__ __launch_bounds__(256) void gemm1_kernel(
    const float* __restrict__ agg,
    const unsigned short* __restrict__ Whi, const unsigned short* __restrict__ Wlo, // layer-0 base
    const float* __restrict__ wal2, const float* __restrict__ war2,                 // layer-1 wal/war
    const float* __restrict__ b0,                                                   // bs layer-0
    unsigned short* __restrict__ hb16, float* __restrict__ el, float* __restrict__ er,
    int n_nodes)
{
  __shared__ unsigned short lds_bh[16384];   // 32KB: one hb-slice
  __shared__ unsigned short lds_bl[16384];
  const int tid = threadIdx.x;
  const int w = tid >> 6;
  const int lane = tid & 63;
  const int lrow = lane & 15;
  const int g = lane >> 4;
  const int node0 = blockIdx.x * 64 + w * 16;

  int arow = node0 + lrow;
  int arow_c = (arow < n_nodes) ? arow : (n_nodes - 1);

  f32x4_t acc[8];
  #pragma unroll
  for (int i = 0; i < 8; ++i) acc[i] = (f32x4_t){0.f, 0.f, 0.f, 0.f};

  for (int hb = 0; hb < 2; ++hb) {
    __syncthreads();
    {
      const uint4* gh = (const uint4*)(Whi + (size_t)hb * 16384);
      const uint4* gl = (const uint4*)(Wlo + (size_t)hb * 16384);
      uint4* lh = (uint4*)lds_bh;
      uint4* ll = (uint4*)lds_bl;
      #pragma unroll
      for (int r = 0; r < 8; ++r) {
        lh[tid + 256 * r] = gh[tid + 256 * r];
        ll[tid + 256 * r] = gl[tid + 256 * r];
      }
    }
    __syncthreads();
    const float* aptr = agg + (size_t)arow_c * 256 + hb * 128 + g * 8;
    #pragma unroll
    for (int s = 0; s < 4; ++s) {
      float4 f0 = *(const float4*)(aptr + s * 32);
      float4 f1 = *(const float4*)(aptr + s * 32 + 4);
      float fv[8] = {f0.x, f0.y, f0.z, f0.w, f1.x, f1.y, f1.z, f1.w};
      bf16x8_t ahi, alo;
      #pragma unroll
      for (int jj = 0; jj < 8; ++jj) {
        unsigned short hb16v = f2bf(fv[jj]);
        float rem = fv[jj] - bfbits((unsigned int)hb16v << 16);
        ahi[jj] = (short)hb16v;
        alo[jj] = (short)f2bf(rem);
      }
      #pragma unroll
      for (int ct = 0; ct < 8; ++ct) {
        bf16x8_t bh = *(const bf16x8_t*)&lds_bh[((s * 8 + ct) * 64 + lane) * 8];
        bf16x8_t bl = *(const bf16x8_t*)&lds_bl[((s * 8 + ct) * 64 + lane) * 8];
        acc[ct] = __builtin_amdgcn_mfma_f32_16x16x32_bf16(ahi, bh, acc[ct], 0, 0, 0);
        acc[ct] = __builtin_amdgcn_mfma_f32_16x16x32_bf16(alo, bh, acc[ct], 0, 0, 0);
        acc[ct] = __builtin_amdgcn_mfma_f32_16x16x32_bf16(ahi, bl, acc[ct], 0, 0, 0);
      }
    }
  }

  // epilogue: v = 0.5*acc + 0.5*(b0[col]+b0[128+col]); hbuf bf16; el2/er2
  float bm[8], alc0[8], alc1[8], arc0[8], arc1[8];
  #pragma unroll
  for (int ct = 0; ct < 8; ++ct) {
    int col = ct * 16 + lrow;
    bm[ct] = 0.5f * (b0[col] + b0[128 + col]);
    alc0[ct] = wal2[col];
    alc1[ct] = wal2[128 + col];
    arc0[ct] = war2[col];
    arc1[ct] = war2[128 + col];
  }
  #pragma unroll
  for (int r = 0; r < 4; ++r) {
    int orow = node0 + g * 4 + r;
    bool ok = orow < n_nodes;
    float pl0 = 0.f, pl1 = 0.f, pr0 = 0.f, pr1 = 0.f;
    #pragma unroll
    for (int ct = 0; ct < 8; ++ct) {
      float v = fmaf(acc[ct][r], 0.5f, bm[ct]);
      pl0 += v * alc0[ct];
      pl1 += v * alc1[ct];
      pr0 += v * arc0[ct];
      pr1 += v * arc1[ct];
      if (ok) hb16[(size_t)orow * 128 + ct * 16 + lrow] = f2bf(v);
    }
    #pragma unroll
    for (int off = 1; off < 16; off <<= 1) {
      pl0 += __shfl_xor(pl0, off);
      pl1 += __shfl_xor(pl1, off);
      pr0 += __shfl_xor(pr0, off);
      pr1 += __shfl_xor(pr1, off);
    }
    if (lrow == 0 && ok) {
      *(float2*)&el[(size_t)orow * 2] = make_float2(pl0, pl1);
      *(float2*)&er[(size_t)orow * 2] = make_float2(pr0, pr1);
    }
  }
}

// ---------------- gemm2: out[:, hb*128:+128] = agg[:,hb,:] @ W1_hb + b1_hb ----

__global__ __launch_bounds__(256) void gemm2_kernel(
    const float* __restrict__ agg,
    const unsigned short* __restrict__ Whi, const unsigned short* __restrict__ Wlo, // layer-1 base
    const float* __restrict__ b1, float* __restrict__ out, int n_nodes)
{
  __shared__ unsigned short lds_bh[16384];
  __shared__ unsigned short lds_bl[16384];
  const int tid = threadIdx.x;
  const int w = tid >> 6;
  const int lane = tid & 63;
  const int lrow = lane & 15;
  const int g = lane >> 4;
  const int hb = blockIdx.y;
  const int node0 = blockIdx.x * 64 + w * 16;

  {
    const uint4* gh = (const uint4*)(Whi + (size_t)hb * 16384);
    const uint4* gl = (const uint4*)(Wlo + (size_t)hb * 16384);
    uint4* lh = (uint4*)lds_bh;
    uint4* ll = (uint4*)lds_bl;
    #pragma unroll
    for (int r = 0; r < 8; ++r) {
      lh[tid + 256 * r] = gh[tid + 256 * r];
      ll[tid + 256 * r] = gl[tid + 256 * r];
    }
  }

  int arow = node0 + lrow;
  int arow_c = (arow < n_nodes) ? arow : (n_nodes - 1);
  const float* aptr = agg + (size_t)arow_c * 256 + hb * 128 + g * 8;
  bf16x8_t ahi[4], alo[4];
  #pragma unroll
  for (int s = 0; s < 4; ++s) {
    float4 f0 = *(const float4*)(aptr + s * 32);
    float4 f1 = *(const float4*)(aptr + s * 32 + 4);
    float fv[8] = {f0.x, f0.y, f0.z, f0.w, f1.x, f1.y, f1.z, f1.w};
    #pragma unroll
    for (int jj = 0; jj < 8; ++jj) {
      unsigned short hb16v = f2bf(fv[jj]);
      float rem = fv[jj] - bfbits((unsigned int)hb16v << 16);
      ahi[s][jj] = (short)hb16v;
      alo[s][jj] = (short)f2bf(rem);
    }
  }

  f32x4_t acc[8];
  #pragma unroll
  for (int i = 0; i < 8; ++i) acc[i] = (f32x4_t){0.f, 0.f, 0.f, 0.f};

  __syncthreads();

  #pragma unroll
  for (int s = 0; s < 4; ++s) {
    #pragma unroll
    for (int ct = 0; ct < 8; ++ct) {
      bf16x8_t bh = *(const bf16x8_t*)&lds_bh[((s * 8 + ct) * 64 + lane) * 8];
      bf16x8_t bl = *(const bf16x8_t*)&lds_bl[((s * 8 + ct) * 64 + lane) * 8];
      acc[ct] = __builtin_amdgcn_mfma_f32_16x16x32_bf16(ahi[s], bh, acc[ct], 0, 0, 0);
      acc[ct] = __builtin_amdgcn_mfma_f32_16x16x32_bf16(alo[s], bh, acc[ct], 0, 0, 0);
      acc[ct] = __builtin_amdgcn_mfma_f32_16x16x32_bf16(ahi[s], bl, acc[ct], 0, 0, 0);
    }
  }

  float bc[8];
  #pragma unroll
  for (int ct = 0; ct < 8; ++ct) bc[ct] = b1[hb * 128 + ct * 16 + lrow];
  #pragma unroll
  for (int r = 0; r < 4; ++r) {
    int orow = node0 + g * 4 + r;
    if (orow >= n_nodes) continue;
    #pragma unroll
    for (int ct = 0; ct < 8; ++ct) {
      out[(size_t)orow * 256 + hb * 128 + ct * 16 + lrow] = acc[ct][r] + bc[ct];
    }
  }
}

// ---------------- launch ----------------

extern "C" void kernel_launch(void* const* d_in, const int* in_sizes, int n_in,
                              void* d_out, int out_size, void* d_ws, size_t ws_size,
                              hipStream_t stream) {
  const float* x   = (const float*)d_in[0];
  const float* Ws  = (const float*)d_in[1];
  const float* als = (const float*)d_in[2];
  const float* ars = (const float*)d_in[3];
  const float* bs  = (const float*)d_in[4];
  const int*   src = (const int*)d_in[5];
  const int*   dst = (const int*)d_in[6];
  const int N = in_sizes[0] / 128;   // 50000
  const int E = in_sizes[5];         // 800000
  float* out = (float*)d_out;

  char* ws = (char*)d_ws;
  auto alloc = [&](size_t bytes) {
    char* p = ws;
    ws += (bytes + 255) & ~(size_t)255;
    return p;
  };
  float* aggb    = (float*)alloc((size_t)N * 256 * 4);           // 51.2MB
  unsigned short* xb16 = (unsigned short*)alloc((size_t)N * 128 * 2);  // 12.8MB
  unsigned short* hb16 = (unsigned short*)alloc((size_t)N * 128 * 2);  // 12.8MB
  int*   srcp    = (int*)alloc((size_t)E * 4);
  int*   offsets = (int*)alloc((size_t)(N + 1) * 4);
  int*   cursor  = (int*)alloc((size_t)N * 4);
  int*   counts  = (int*)alloc((size_t)N * 4);
  float* el      = (float*)alloc((size_t)N * 2 * 4);
  float* er      = (float*)alloc((size_t)N * 2 * 4);
  float* wal     = (float*)alloc((size_t)512 * 4);
  float* war     = (float*)alloc((size_t)512 * 4);
  unsigned int* tstate = (unsigned int*)alloc((size_t)64 * 4);
  unsigned short* Whi = (unsigned short*)alloc((size_t)65536 * 2);
  unsigned short* Wlo = (unsigned short*)alloc((size_t)65536 * 2);

  const int nb = (N + 1023) / 1024;                 // 49 scan tiles
  const int nxb = (N * 128 + 1023) / 1024;          // 6250 x->bf16 blocks
  const int init_blocks = 36 + nxb + (N + 255) / 256;
  const int ngrp = (N + 3) / 4;                     // 12500
  const int ntiles = (N + 63) / 64;                 // 782

  init_kernel<<<dim3(init_blocks), dim3(256), 0, stream>>>(
      Ws, als, ars, x, Whi, Wlo, wal, war, xb16, counts, tstate, N);
  hist_kernel<<<dim3((E + 255) / 256), dim3(256), 0, stream>>>(dst, counts, E);
  scan_kernel<<<dim3(nb), dim3(256), 0, stream>>>(counts, offsets, cursor, tstate, N);
  scatter_kernel<<<dim3((E + 255) / 256), dim3(256), 0, stream>>>(src, dst, cursor, srcp, E);

  // layer 1
  elr_kernel<<<dim3(ngrp), dim3(256), 0, stream>>>(x, wal, war, el, er, N);
  aggregate_kernel<<<dim3(ngrp), dim3(256), 0, stream>>>(xb16, el, er, srcp, offsets, aggb, N);
  gemm1_kernel<<<dim3(ntiles), dim3(256), 0, stream>>>(
      aggb, Whi, Wlo, wal + 256, war + 256, bs, hb16, el, er, N);
  // layer 2
  aggregate_kernel<<<dim3(ngrp), dim3(256), 0, stream>>>(hb16, el, er, srcp, offsets, aggb, N);
  gemm2_kernel<<<dim3(ntiles, 2), dim3(256), 0, stream>>>(
      aggb, Whi + 32768, Wlo + 32768, bs + 256, out, N);
}